// Round 4
// baseline (227.696 us; speedup 1.0000x reference)
//
#include <hip/hip_runtime.h>
#include <hip/hip_bf16.h>
#include <cstddef>
#include <cstdint>

#define FIN   128
#define HID   64
#define H1    4
#define NGRAPH 512
#define BCAP  8192   // bucket capacity (mean 4081, +64 sigma safe)

typedef short bf16x8 __attribute__((ext_vector_type(8)));
typedef float f32x4  __attribute__((ext_vector_type(4)));
typedef float f32x2  __attribute__((ext_vector_type(2)));

#if defined(__has_builtin)
#if __has_builtin(__builtin_amdgcn_cvt_f32_fp8) && __has_builtin(__builtin_amdgcn_cvt_pk_fp8_f32)
#define HAVE_HW_FP8 1
#endif
#if __has_builtin(__builtin_amdgcn_cvt_pk_f32_fp8)
#define HAVE_HW_FP8_PK 1
#endif
#endif

__device__ __forceinline__ float wave_reduce_sum(float v) {
  #pragma unroll
  for (int off = 32; off > 0; off >>= 1) v += __shfl_down(v, off, 64);
  return v;
}

__device__ __forceinline__ float leaky02(float x) {
  return x > 0.0f ? x : 0.2f * x;
}

__device__ __forceinline__ float bf2f(unsigned short u) {
  union { unsigned int i; float f; } v; v.i = ((unsigned int)u) << 16; return v.f;
}
__device__ __forceinline__ unsigned short f2bf(float f) {
  union { float f; unsigned int i; } v; v.f = f;
  unsigned int b = v.i;
  return (unsigned short)((b + 0x7FFFu + ((b >> 16) & 1u)) >> 16);  // RNE
}

#ifndef HAVE_HW_FP8
__device__ __forceinline__ unsigned char f2fp8_1(float f) {
  unsigned int u = __float_as_uint(f);
  unsigned int s = u >> 31;
  u &= 0x7fffffffu;
  if (u > 0x43e00000u) u = 0x43e00000u;
  unsigned int b = u + (0x0007FFFFu + ((u >> 20) & 1u));
  int e = (int)(b >> 23) - 127;
  unsigned int m = (b >> 20) & 7u;
  unsigned char o;
  if (e < -9) o = 0;
  else if (e < -6) { int sh = -6 - e; o = (unsigned char)((8u | m) >> sh); }
  else if (e > 8) o = 0x7e;
  else o = (unsigned char)(((e + 7) << 3) | m);
  return o | (unsigned char)(s << 7);
}
#endif
__device__ __forceinline__ float fp8tof_1(unsigned char b) {
  unsigned int s = b >> 7, e = (b >> 3) & 15u, m = b & 7u;
  float v = (e == 0) ? (float)m * 0.001953125f
                     : (float)(8u + m) * __uint_as_float((117u + e) << 23);
  return s ? -v : v;
}

__device__ __forceinline__ unsigned char f2fp8(float f) {
#ifdef HAVE_HW_FP8
  return (unsigned char)(__builtin_amdgcn_cvt_pk_fp8_f32(f, f, 0u, false) & 0xffu);
#else
  return f2fp8_1(f);
#endif
}

// fused: a{0..3} += p * fp8x4(hw)  — packed decode when HW supports it
__device__ __forceinline__ void fma4_fp8(unsigned int hw, float p,
                                         float& a0, float& a1, float& a2, float& a3) {
#ifdef HAVE_HW_FP8_PK
  f32x2 lo = __builtin_amdgcn_cvt_pk_f32_fp8((int)hw, false);
  f32x2 hi = __builtin_amdgcn_cvt_pk_f32_fp8((int)hw, true);
  a0 = fmaf(p, lo.x, a0);
  a1 = fmaf(p, lo.y, a1);
  a2 = fmaf(p, hi.x, a2);
  a3 = fmaf(p, hi.y, a3);
#elif defined(HAVE_HW_FP8)
  a0 = fmaf(p, __builtin_amdgcn_cvt_f32_fp8(hw, 0), a0);
  a1 = fmaf(p, __builtin_amdgcn_cvt_f32_fp8(hw, 1), a1);
  a2 = fmaf(p, __builtin_amdgcn_cvt_f32_fp8(hw, 2), a2);
  a3 = fmaf(p, __builtin_amdgcn_cvt_f32_fp8(hw, 3), a3);
#else
  a0 = fmaf(p, fp8tof_1((unsigned char)(hw & 0xffu)), a0);
  a1 = fmaf(p, fp8tof_1((unsigned char)((hw >> 8) & 0xffu)), a1);
  a2 = fmaf(p, fp8tof_1((unsigned char)((hw >> 16) & 0xffu)), a2);
  a3 = fmaf(p, fp8tof_1((unsigned char)((hw >> 24) & 0xffu)), a3);
#endif
}

// ---------------------------------------------------------------------------
// bpart: [preamble] W transposes + graph bounds (grid-stride), then partition
// edges into fixed-capacity buckets; pack src | (dstlocal<<16).
#define P3K 8
__global__ __launch_bounds__(256)
void bpart_kernel(const int* __restrict__ src, const int* __restrict__ dst,
                  int* __restrict__ bucketFill, unsigned int* __restrict__ bucketBuf,
                  const float* __restrict__ W1, const float* __restrict__ W2,
                  unsigned short* __restrict__ W1T, unsigned short* __restrict__ W2T,
                  const int* __restrict__ batch, int* __restrict__ gstart,
                  int* __restrict__ gend, int E, int N, int nbuck) {
  int tid = threadIdx.x;
  int stride = gridDim.x * 256;
  int t0 = blockIdx.x * 256 + tid;
  for (int u = t0; u < 256 * 128; u += stride) {   // W1T[n][k] = W1[k][n]
    int n = u >> 7, k = u & 127;
    W1T[u] = f2bf(W1[(size_t)k * 256 + n]);
  }
  for (int u = t0; u < 64 * 256; u += stride) {    // W2T[n][k] = W2[k][n]
    int n = u >> 8, k = u & 255;
    W2T[u] = f2bf(W2[(size_t)k * 64 + n]);
  }
  for (int i = t0; i < N; i += stride) {
    int g = batch[i];
    if (i == 0 || batch[i - 1] != g) gstart[g] = i;
    if (i == N - 1 || batch[i + 1] != g) gend[g] = i + 1;
  }

  __shared__ int lhist[256];
  __shared__ int lbase[256];
  int chunk = 256 * P3K;
  for (int start = blockIdx.x * chunk; start < E; start += gridDim.x * chunk) {
    lhist[tid] = 0;
    __syncthreads();
    int mybuck[P3K]; unsigned int mypack[P3K]; int myrank[P3K];
    #pragma unroll
    for (int k = 0; k < P3K; k++) {
      int i = start + k * 256 + tid;
      if (i < E) {
        int d = dst[i];
        int b = d >> 8;
        mybuck[k] = b;
        mypack[k] = (unsigned int)src[i] | ((unsigned int)(d & 255) << 16);
        myrank[k] = atomicAdd(&lhist[b], 1);
      } else mybuck[k] = -1;
    }
    __syncthreads();
    if (tid < nbuck) lbase[tid] = (lhist[tid] > 0) ? atomicAdd(&bucketFill[tid], lhist[tid]) : 0;
    __syncthreads();
    #pragma unroll
    for (int k = 0; k < P3K; k++) {
      if (mybuck[k] >= 0) {
        int b = mybuck[k];
        int pos = lbase[b] + myrank[k];
        if (pos < BCAP) bucketBuf[((size_t)b << 13) + pos] = mypack[k];
      }
    }
    __syncthreads();
  }
}

// ---------------------------------------------------------------------------
// merged bbuild + gemm1: blocks [0,nbuck) build per-bucket CSR; blocks
// [nbuck, nbuck+gridG) do GEMM1 (independent of CSR).
__global__ __launch_bounds__(256)
void bbuild_gemm1_kernel(const unsigned int* __restrict__ bucketBuf,
                         const int* __restrict__ bucketFill,
                         int* __restrict__ rowstart, int* __restrict__ rowend,
                         unsigned short* __restrict__ csr,
                         const float* __restrict__ X, const unsigned short* __restrict__ W1T,
                         unsigned char* __restrict__ h1f8,
                         const float* __restrict__ a_src, const float* __restrict__ a_dst,
                         float* __restrict__ asv, float* __restrict__ adv,
                         int N, int nbuck) {
  __shared__ union {
    struct { unsigned short As[64][136]; unsigned short Bs[256][40]; } g;
    struct { int ldeg[256]; int lscan[256]; int lfill[256]; } b;
  } sm;
  int tid = threadIdx.x;

  if (blockIdx.x < (unsigned)nbuck) {
    // ---- bbuild path ----
    int b = blockIdx.x;
    int r0 = b << 13;
    int cnt = bucketFill[b]; if (cnt > BCAP) cnt = BCAP;
    int nb0 = b << 8;
    sm.b.ldeg[tid] = 0;
    __syncthreads();
    for (int j = tid; j < cnt; j += 256)
      atomicAdd(&sm.b.ldeg[bucketBuf[r0 + j] >> 16], 1);
    __syncthreads();
    int v = sm.b.ldeg[tid];
    sm.b.lscan[tid] = v;
    __syncthreads();
    for (int off = 1; off < 256; off <<= 1) {
      int u = (tid >= off) ? sm.b.lscan[tid - off] : 0;
      __syncthreads();
      sm.b.lscan[tid] += u;
      __syncthreads();
    }
    int excl = sm.b.lscan[tid] - v;
    sm.b.lfill[tid] = excl;
    if (nb0 + tid < N) {
      rowstart[nb0 + tid] = r0 + excl;
      rowend[nb0 + tid]   = r0 + excl + v;
    }
    __syncthreads();
    for (int j = tid; j < cnt; j += 256) {
      unsigned int p = bucketBuf[r0 + j];
      int pos = r0 + atomicAdd(&sm.b.lfill[p >> 16], 1);
      csr[pos] = (unsigned short)(p & 0xffffu);
    }
    return;
  }

  // ---- gemm1 path ----
  int t = tid;
  int w = t >> 6, lane = t & 63;
  int quad = lane >> 4, l16 = lane & 15;
  int blockRow = (blockIdx.x - nbuck) * 64;

  {
    int node = t >> 2, kp = (t & 3) * 32;
    int gn = blockRow + node; if (gn >= N) gn = N - 1;
    const float4* xp = (const float4*)(X + (size_t)gn * 128 + kp);
    #pragma unroll
    for (int i = 0; i < 4; i++) {
      float4 va = xp[2 * i], vb = xp[2 * i + 1];
      union { unsigned short u[8]; uint4 v; } r;
      r.u[0] = f2bf(va.x); r.u[1] = f2bf(va.y); r.u[2] = f2bf(va.z); r.u[3] = f2bf(va.w);
      r.u[4] = f2bf(vb.x); r.u[5] = f2bf(vb.y); r.u[6] = f2bf(vb.z); r.u[7] = f2bf(vb.w);
      *(uint4*)&sm.g.As[node][kp + i * 8] = r.v;
    }
  }

  f32x4 acc[4][4];
  #pragma unroll
  for (int i = 0; i < 4; i++)
    #pragma unroll
    for (int j = 0; j < 4; j++) acc[i][j] = (f32x4){0.f, 0.f, 0.f, 0.f};

  for (int kc = 0; kc < FIN; kc += 32) {
    {
      const unsigned short* wp = W1T + (size_t)t * 128 + kc;
      #pragma unroll
      for (int i = 0; i < 4; i++) {
        uint4 v = *(const uint4*)(wp + i * 8);
        *(uint4*)&sm.g.Bs[t][i * 8] = v;
      }
    }
    __syncthreads();
    bf16x8 af[4], bfr[4];
    #pragma unroll
    for (int mt = 0; mt < 4; mt++)
      af[mt] = *(const bf16x8*)&sm.g.As[mt * 16 + l16][kc + quad * 8];
    #pragma unroll
    for (int nt = 0; nt < 4; nt++)
      bfr[nt] = *(const bf16x8*)&sm.g.Bs[w * 64 + nt * 16 + l16][quad * 8];
    #pragma unroll
    for (int mt = 0; mt < 4; mt++)
      #pragma unroll
      for (int nt = 0; nt < 4; nt++)
        acc[mt][nt] = __builtin_amdgcn_mfma_f32_16x16x32_bf16(af[mt], bfr[nt], acc[mt][nt], 0, 0, 0);
    __syncthreads();
  }

  float a_s[4], a_d[4];
  #pragma unroll
  for (int nt = 0; nt < 4; nt++) {
    a_s[nt] = a_src[w * 64 + nt * 16 + l16];
    a_d[nt] = a_dst[w * 64 + nt * 16 + l16];
  }
  #pragma unroll
  for (int mt = 0; mt < 4; mt++) {
    #pragma unroll
    for (int reg = 0; reg < 4; reg++) {
      int node = blockRow + mt * 16 + quad * 4 + reg;
      bool ok = node < N;
      float ps = 0.0f, pd = 0.0f;
      #pragma unroll
      for (int nt = 0; nt < 4; nt++) {
        float v = acc[mt][nt][reg];
        ps = fmaf(v, a_s[nt], ps);
        pd = fmaf(v, a_d[nt], pd);
        if (ok) h1f8[(size_t)node * 256 + w * 64 + nt * 16 + l16] = f2fp8(v);
      }
      #pragma unroll
      for (int off = 8; off > 0; off >>= 1) {
        ps += __shfl_xor(ps, off, 16);
        pd += __shfl_xor(pd, off, 16);
      }
      if (l16 == 0 && ok) {
        asv[(size_t)node * 4 + w] = ps;
        adv[(size_t)node * 4 + w] = pd;
      }
    }
  }
}

// ---------------------------------------------------------------------------
// FUSED aggregation-1 + GEMM2: 8 waves/block, wave wv gathers node nb+wv
// (gather loop identical to the proven agg1 structure: scalar-addressed
// uniform-row loads, 8 in flight, in-loop ssum). Epilogue writes the bf16
// out1 row into LDS (not global); after one __syncthreads wave 0 computes
// h2 = out1 @ W2 via MFMA (M=16 pad, 8 valid rows), fused attn2, h2f8 out.
// Removes the 51 MB out1b round-trip and the gemm2 dispatch.
__global__ __launch_bounds__(512, 4)
void agg1g2_kernel(const unsigned char* __restrict__ h1f8, const int* __restrict__ rowstart,
                   const int* __restrict__ rowend, const unsigned short* __restrict__ csr,
                   const float* __restrict__ asv, const float* __restrict__ adv,
                   const float* __restrict__ b1, const unsigned short* __restrict__ W2T,
                   unsigned char* __restrict__ h2f8,
                   const float* __restrict__ a_src2, const float* __restrict__ a_dst2,
                   float* __restrict__ asv2, float* __restrict__ adv2, int N) {
  __shared__ int   sbuf[8][64];
  __shared__ float pbuf[8][4][68];    // [wave][head][edge]
  __shared__ unsigned short o1s[16][288];  // bf16 out1 rows (8 valid), pad stride
  int wv   = threadIdx.x >> 6;
  int lane = threadIdx.x & 63;
  int nb = blockIdx.x * 8;
  int n = nb + wv;

  if (n < N) {
    int r0 = rowstart[n], r1 = rowend[n];
    float4 ad = *(const float4*)(adv + (size_t)n * 4);
    float4 asn = *(const float4*)(asv + (size_t)n * 4);
    int hsel = lane >> 4;

    float es0 = leaky02(asn.x + ad.x);
    float es1 = leaky02(asn.y + ad.y);
    float es2 = leaky02(asn.z + ad.z);
    float es3 = leaky02(asn.w + ad.w);
    float esel = hsel == 0 ? es0 : (hsel == 1 ? es1 : (hsel == 2 ? es2 : es3));

    float ssum = 0.0f;
    float a0 = 0, a1 = 0, a2 = 0, a3 = 0;

    for (int base = r0; base < r1; base += 64) {
      int j = base + lane;
      int cnt = min(64, r1 - base);
      if (j < r1) {
        int s = csr[j];
        float4 as = *(const float4*)(asv + (size_t)s * 4);
        sbuf[wv][lane] = s;
        pbuf[wv][0][lane] = __expf(leaky02(as.x + ad.x));
        pbuf[wv][1][lane] = __expf(leaky02(as.y + ad.y));
        pbuf[wv][2][lane] = __expf(leaky02(as.z + ad.z));
        pbuf[wv][3][lane] = __expf(leaky02(as.w + ad.w));
      }
      __threadfence_block();

      int c = 0;
      for (; c + 8 <= cnt; c += 8) {
        int4 sv0 = *(const int4*)&sbuf[wv][c];
        int4 sv1 = *(const int4*)&sbuf[wv][c + 4];
        int sc0 = __builtin_amdgcn_readfirstlane(sv0.x);
        int sc1 = __builtin_amdgcn_readfirstlane(sv0.y);
        int sc2 = __builtin_amdgcn_readfirstlane(sv0.z);
        int sc3 = __builtin_amdgcn_readfirstlane(sv0.w);
        int sc4 = __builtin_amdgcn_readfirstlane(sv1.x);
        int sc5 = __builtin_amdgcn_readfirstlane(sv1.y);
        int sc6 = __builtin_amdgcn_readfirstlane(sv1.z);
        int sc7 = __builtin_amdgcn_readfirstlane(sv1.w);
        unsigned int hw0 = *((const unsigned int*)(h1f8 + ((size_t)sc0 << 8)) + lane);
        unsigned int hw1 = *((const unsigned int*)(h1f8 + ((size_t)sc1 << 8)) + lane);
        unsigned int hw2 = *((const unsigned int*)(h1f8 + ((size_t)sc2 << 8)) + lane);
        unsigned int hw3 = *((const unsigned int*)(h1f8 + ((size_t)sc3 << 8)) + lane);
        unsigned int hw4 = *((const unsigned int*)(h1f8 + ((size_t)sc4 << 8)) + lane);
        unsigned int hw5 = *((const unsigned int*)(h1f8 + ((size_t)sc5 << 8)) + lane);
        unsigned int hw6 = *((const unsigned int*)(h1f8 + ((size_t)sc6 << 8)) + lane);
        unsigned int hw7 = *((const unsigned int*)(h1f8 + ((size_t)sc7 << 8)) + lane);
        float4 pva = *(const float4*)&pbuf[wv][hsel][c];
        float4 pvb = *(const float4*)&pbuf[wv][hsel][c + 4];
        ssum += (pva.x + pva.y) + (pva.z + pva.w) + (pvb.x + pvb.y) + (pvb.z + pvb.w);
        fma4_fp8(hw0, pva.x, a0, a1, a2, a3);
        fma4_fp8(hw1, pva.y, a0, a1, a2, a3);
        fma4_fp8(hw2, pva.z, a0, a1, a2, a3);
        fma4_fp8(hw3, pva.w, a0, a1, a2, a3);
        fma4_fp8(hw4, pvb.x, a0, a1, a2, a3);
        fma4_fp8(hw5, pvb.y, a0, a1, a2, a3);
        fma4_fp8(hw6, pvb.z, a0, a1, a2, a3);
        fma4_fp8(hw7, pvb.w, a0, a1, a2, a3);
      }
      for (; c + 4 <= cnt; c += 4) {
        int4 sv = *(const int4*)&sbuf[wv][c];
        int sc0 = __builtin_amdgcn_readfirstlane(sv.x);
        int sc1 = __builtin_amdgcn_readfirstlane(sv.y);
        int sc2 = __builtin_amdgcn_readfirstlane(sv.z);
        int sc3 = __builtin_amdgcn_readfirstlane(sv.w);
        unsigned int hw0 = *((const unsigned int*)(h1f8 + ((size_t)sc0 << 8)) + lane);
        unsigned int hw1 = *((const unsigned int*)(h1f8 + ((size_t)sc1 << 8)) + lane);
        unsigned int hw2 = *((const unsigned int*)(h1f8 + ((size_t)sc2 << 8)) + lane);
        unsigned int hw3 = *((const unsigned int*)(h1f8 + ((size_t)sc3 << 8)) + lane);
        float4 pv = *(const float4*)&pbuf[wv][hsel][c];
        ssum += (pv.x + pv.y) + (pv.z + pv.w);
        fma4_fp8(hw0, pv.x, a0, a1, a2, a3);
        fma4_fp8(hw1, pv.y, a0, a1, a2, a3);
        fma4_fp8(hw2, pv.z, a0, a1, a2, a3);
        fma4_fp8(hw3, pv.w, a0, a1, a2, a3);
      }
      for (; c < cnt; c++) {
        int sc = __builtin_amdgcn_readfirstlane(sbuf[wv][c]);
        float psel = pbuf[wv][hsel][c];
        unsigned int hw = *((const unsigned int*)(h1f8 + ((size_t)sc << 8)) + lane);
        ssum += psel;
        fma4_fp8(hw, psel, a0, a1, a2, a3);
      }
      __threadfence_block();
    }

    {
      float psel = __expf(esel);   // self-loop
      ssum += psel;
      unsigned int hw = *((const unsigned int*)(h1f8 + ((size_t)n << 8)) + lane);
      fma4_fp8(hw, psel, a0, a1, a2, a3);
    }

    float inv = 1.0f / (ssum + 1e-16f);
    int d0 = lane * 4;
    float4 bv = *(const float4*)(b1 + d0);
    float v0 = a0 * inv + bv.x;
    float v1 = a1 * inv + bv.y;
    float v2 = a2 * inv + bv.z;
    float v3 = a3 * inv + bv.w;
    ushort4 o;
    o.x = f2bf(v0 > 0 ? v0 : 0.0f);
    o.y = f2bf(v1 > 0 ? v1 : 0.0f);
    o.z = f2bf(v2 > 0 ? v2 : 0.0f);
    o.w = f2bf(v3 > 0 ? v3 : 0.0f);
    *(ushort4*)&o1s[wv][d0] = o;    // LDS instead of global out1b
  }

  __syncthreads();

  // ---- wave 0: h2 = o1s[0:8] @ W2T^T (M=16 pad), fused attn2 ----
  if (threadIdx.x < 64) {
    int quad = lane >> 4, l16 = lane & 15;
    f32x4 acc[4];
    #pragma unroll
    for (int j = 0; j < 4; j++) acc[j] = (f32x4){0.f, 0.f, 0.f, 0.f};

    for (int kc = 0; kc < 256; kc += 32) {
      bf16x8 af = *(const bf16x8*)&o1s[l16][kc + quad * 8];
      #pragma unroll
      for (int nt = 0; nt < 4; nt++) {
        bf16x8 bfr = *(const bf16x8*)(W2T + (size_t)(nt * 16 + l16) * 256 + kc + quad * 8);
        acc[nt] = __builtin_amdgcn_mfma_f32_16x16x32_bf16(af, bfr, acc[nt], 0, 0, 0);
      }
    }

    float a_s[4], a_d[4];
    #pragma unroll
    for (int nt = 0; nt < 4; nt++) {
      a_s[nt] = a_src2[nt * 16 + l16];
      a_d[nt] = a_dst2[nt * 16 + l16];
    }
    #pragma unroll
    for (int reg = 0; reg < 4; reg++) {
      int rq = quad * 4 + reg;
      int node = nb + rq;
      bool ok = (rq < 8) && (node < N);
      float ps = 0.0f, pd = 0.0f;
      #pragma unroll
      for (int nt = 0; nt < 4; nt++) {
        float v = acc[nt][reg];
        ps = fmaf(v, a_s[nt], ps);
        pd = fmaf(v, a_d[nt], pd);
        if (ok) h2f8[(size_t)node * 64 + nt * 16 + l16] = f2fp8(v);
      }
      #pragma unroll
      for (int off = 8; off > 0; off >>= 1) {
        ps += __shfl_xor(ps, off, 16);
        pd += __shfl_xor(pd, off, 16);
      }
      if (l16 == 0 && ok) { asv2[node] = ps; adv2[node] = pd; }
    }
  }
}

// aggregation layer 2: m=0; per-lane psum; up to 16 edges per wave-iter
// (4 per quad, 4 loads in flight); q accumulated per-quad in-loop, folded
// into the cross-quad a-reduction. h2 output stored bf16.
__global__ __launch_bounds__(256)
void agg2_kernel(const unsigned char* __restrict__ h2f8, const int* __restrict__ rowstart,
                 const int* __restrict__ rowend, const unsigned short* __restrict__ csr,
                 const float* __restrict__ asv, const float* __restrict__ adv,
                 const float* __restrict__ b2, unsigned short* __restrict__ h2b, int N) {
  __shared__ int   sbuf[4][64];
  __shared__ float pbuf[4][64];
  int wv   = threadIdx.x >> 6;
  int lane = threadIdx.x & 63;
  int quad = lane >> 4, l16 = lane & 15;
  int n = blockIdx.x * 4 + wv;
  if (n >= N) return;
  int r0 = rowstart[n], r1 = rowend[n];
  float ad = adv[n];
  float eself = leaky02(asv[n] + ad);
  float q = 0.0f;
  float a0 = 0, a1 = 0, a2 = 0, a3 = 0;

  for (int base = r0; base < r1; base += 64) {
    int j = base + lane;
    int cnt = min(64, r1 - base);
    if (j < r1) {
      int s = csr[j];
      sbuf[wv][lane] = s;
      pbuf[wv][lane] = __expf(leaky02(asv[s] + ad));
    }
    __threadfence_block();

    int c = 0;
    for (; c + 16 <= cnt; c += 16) {
      int scA = sbuf[wv][c + quad];
      int scB = sbuf[wv][c + 4 + quad];
      int scC = sbuf[wv][c + 8 + quad];
      int scD = sbuf[wv][c + 12 + quad];
      float pA = pbuf[wv][c + quad];
      float pB = pbuf[wv][c + 4 + quad];
      float pC = pbuf[wv][c + 8 + quad];
      float pD = pbuf[wv][c + 12 + quad];
      unsigned int hwA = *((const unsigned int*)(h2f8 + ((size_t)scA << 6)) + l16);
      unsigned int hwB = *((const unsigned int*)(h2f8 + ((size_t)scB << 6)) + l16);
      unsigned int hwC = *((const unsigned int*)(h2f8 + ((size_t)scC << 6)) + l16);
      unsigned int hwD = *((const unsigned int*)(h2f8 + ((size_t)scD << 6)) + l16);
      q += (pA + pB) + (pC + pD);
      fma4_fp8(hwA, pA, a0, a1, a2, a3);
      fma4_fp8(hwB, pB, a0, a1, a2, a3);
      fma4_fp8(hwC, pC, a0, a1, a2, a3);
      fma4_fp8(hwD, pD, a0, a1, a2, a3);
    }
    for (; c + 8 <= cnt; c += 8) {
      int scA = sbuf[wv][c + quad];
      int scB = sbuf[wv][c + 4 + quad];
      float pA = pbuf[wv][c + quad];
      float pB = pbuf[wv][c + 4 + quad];
      unsigned int hwA = *((const unsigned int*)(h2f8 + ((size_t)scA << 6)) + l16);
      unsigned int hwB = *((const unsigned int*)(h2f8 + ((size_t)scB << 6)) + l16);
      q += pA + pB;
      fma4_fp8(hwA, pA, a0, a1, a2, a3);
      fma4_fp8(hwB, pB, a0, a1, a2, a3);
    }
    for (; c + 4 <= cnt; c += 4) {
      int sc = sbuf[wv][c + quad];
      float p1 = pbuf[wv][c + quad];
      unsigned int hw = *((const unsigned int*)(h2f8 + ((size_t)sc << 6)) + l16);
      q += p1;
      fma4_fp8(hw, p1, a0, a1, a2, a3);
    }
    int rem = cnt - c;
    if (quad < rem) {
      int sc = sbuf[wv][c + quad];
      float p1 = pbuf[wv][c + quad];
      unsigned int hw = *((const unsigned int*)(h2f8 + ((size_t)sc << 6)) + l16);
      q += p1;
      fma4_fp8(hw, p1, a0, a1, a2, a3);
    }
    __threadfence_block();
  }

  // cross-quad reduce: a-partials and the per-quad q in one pass
  #pragma unroll
  for (int off = 16; off <= 32; off <<= 1) {
    q  += __shfl_xor(q,  off, 64);
    a0 += __shfl_xor(a0, off, 64);
    a1 += __shfl_xor(a1, off, 64);
    a2 += __shfl_xor(a2, off, 64);
    a3 += __shfl_xor(a3, off, 64);
  }
  float ssum = q;

  {
    float p = __expf(eself);
    ssum += p;
    unsigned int hw = *((const unsigned int*)(h2f8 + ((size_t)n << 6)) + l16);
    fma4_fp8(hw, p, a0, a1, a2, a3);
  }

  if (quad == 0) {
    float inv = 1.0f / (ssum + 1e-16f);
    float4 bv = *(const float4*)(b2 + l16 * 4);
    float v0 = a0 * inv + bv.x;
    float v1 = a1 * inv + bv.y;
    float v2 = a2 * inv + bv.z;
    float v3 = a3 * inv + bv.w;
    ushort4 o;
    o.x = f2bf(v0 > 0 ? v0 : 0.0f);
    o.y = f2bf(v1 > 0 ? v1 : 0.0f);
    o.z = f2bf(v2 > 0 ? v2 : 0.0f);
    o.w = f2bf(v3 > 0 ? v3 : 0.0f);
    *(ushort4*)(h2b + (size_t)n * 64 + l16 * 4) = o;
  }
}

// ---------------------------------------------------------------------------
// mean pool (bf16 h2) + classifier + log_softmax; one 4-wave block per graph
__global__ __launch_bounds__(256)
void pool_kernel(const unsigned short* __restrict__ h2b, const int* __restrict__ gstart,
                 const int* __restrict__ gend, const float* __restrict__ Wc,
                 const float* __restrict__ bc, float* __restrict__ out) {
  int g = blockIdx.x;
  int w = threadIdx.x >> 6, lane = threadIdx.x & 63;
  int s = gstart[g], e = gend[g];
  float acc = 0.0f;
  for (int n = s + w; n < e; n += 4) acc += bf2f(h2b[(size_t)n * 64 + lane]);
  __shared__ float red[4][64];
  red[w][lane] = acc;
  __syncthreads();
  if (w == 0) {
    float v = red[0][lane] + red[1][lane] + red[2][lane] + red[3][lane];
    float pooled = (e > s) ? v / (float)(e - s) : 0.0f;
    float l0 = wave_reduce_sum(pooled * Wc[lane * 2 + 0]);
    float l1 = wave_reduce_sum(pooled * Wc[lane * 2 + 1]);
    if (lane == 0) {
      l0 += bc[0]; l1 += bc[1];
      float mx = fmaxf(l0, l1);
      float lse = mx + logf(__expf(l0 - mx) + __expf(l1 - mx));
      out[g * 2 + 0] = l0 - lse;
      out[g * 2 + 1] = l1 - lse;
    }
  }
}

// ---------------------------------------------------------------------------
extern "C" void kernel_launch(void* const* d_in, const int* in_sizes, int n_in,
                              void* d_out, int out_size, void* d_ws, size_t ws_size,
                              hipStream_t stream) {
  const float* x      = (const float*)d_in[0];
  const int*   ei     = (const int*)d_in[1];
  const int*   batch  = (const int*)d_in[2];
  const float* W1     = (const float*)d_in[3];
  const float* a_src1 = (const float*)d_in[4];
  const float* a_dst1 = (const float*)d_in[5];
  const float* b1     = (const float*)d_in[6];
  const float* W2     = (const float*)d_in[7];
  const float* a_src2 = (const float*)d_in[8];
  const float* a_dst2 = (const float*)d_in[9];
  const float* b2     = (const float*)d_in[10];
  const float* Wc     = (const float*)d_in[11];
  const float* bc     = (const float*)d_in[12];
  float* out = (float*)d_out;

  const int N = in_sizes[0] / FIN;      // 50000
  const int E = in_sizes[1] / 2;        // 800000
  const int* srcArr = ei;
  const int* dstArr = ei + E;
  const int nbuck = (N + 255) >> 8;     // 196

  char* base = (char*)d_ws;
  size_t off = 0;
  auto alloc = [&](size_t bytes) -> void* {
    void* p = base + off;
    off = (off + bytes + 255) & ~(size_t)255;
    return p;
  };
  unsigned short* W1T  = (unsigned short*)alloc((size_t)256 * 128 * 2);
  unsigned short* W2T  = (unsigned short*)alloc((size_t)64 * 256 * 2);
  unsigned char*  h1f8 = (unsigned char*)alloc((size_t)N * 256);
  unsigned char*  h2f8 = (unsigned char*)alloc((size_t)N * 64);
  unsigned short* h2b  = (unsigned short*)alloc((size_t)N * 64 * 2);
  float* asv1  = (float*)alloc((size_t)N * 4 * 4);
  float* adv1  = (float*)alloc((size_t)N * 4 * 4);
  float* asv2  = (float*)alloc((size_t)N * 4);
  float* adv2  = (float*)alloc((size_t)N * 4);
  // zero-init region: bucketFill, gstart, gend contiguous
  int*   bucketFill= (int*)alloc(256 * 4);
  int*   gstart= (int*)alloc(NGRAPH * 4);
  int*   gend  = (int*)alloc(NGRAPH * 4);
  size_t zspan = (size_t)((char*)gend + NGRAPH * 4 - (char*)bucketFill);
  int*   rowstart = (int*)alloc((size_t)N * 4);
  int*   rowend   = (int*)alloc((size_t)N * 4);
  unsigned int* bucketBuf = (unsigned int*)alloc((size_t)nbuck * BCAP * 4);
  unsigned short* csr = (unsigned short*)alloc((size_t)nbuck * BCAP * 2);
  (void)ws_size; (void)n_in; (void)out_size;

  int gridWv = (N + 3) / 4;
  int gridG  = (N + 63) / 64;
  int gridF  = (N + 7) / 8;
  int gridP3 = (E + 256 * P3K - 1) / (256 * P3K);
  if (gridP3 > 1024) gridP3 = 1024;

  hipMemsetAsync(bucketFill, 0, zspan, stream);
  bpart_kernel<<<gridP3, 256, 0, stream>>>(srcArr, dstArr, bucketFill, bucketBuf,
                                           W1, W2, W1T, W2T, batch, gstart, gend,
                                           E, N, nbuck);
  // merged: CSR build (blocks < nbuck) + GEMM1 (rest)
  bbuild_gemm1_kernel<<<nbuck + gridG, 256, 0, stream>>>(
      bucketBuf, bucketFill, rowstart, rowend, csr,
      x, W1T, h1f8, a_src1, a_dst1, asv1, adv1, N, nbuck);

  // fused agg1 + gemm2 (out1b round-trip + gemm2 dispatch removed)
  agg1g2_kernel<<<gridF, 512, 0, stream>>>(h1f8, rowstart, rowend, csr, asv1, adv1,
                                           b1, W2T, h2f8, a_src2, a_dst2,
                                           asv2, adv2, N);

  agg2_kernel<<<gridWv, 256, 0, stream>>>(h2f8, rowstart, rowend, csr, asv2, adv2, b2, h2b, N);

  // pool + classify
  pool_kernel<<<NGRAPH, 256, 0, stream>>>(h2b, gstart, gend, Wc, bc, out);
}

// Round 5
// 218.083 us; speedup vs baseline: 1.0441x; 1.0441x over previous
//
#include <hip/hip_runtime.h>
#include <hip/hip_bf16.h>
#include <cstddef>
#include <cstdint>

#define FIN   128
#define HID   64
#define H1    4
#define NGRAPH 512
#define BCAP  8192   // bucket capacity (mean 4081, +64 sigma safe)

typedef short bf16x8 __attribute__((ext_vector_type(8)));
typedef float f32x4  __attribute__((ext_vector_type(4)));
typedef float f32x2  __attribute__((ext_vector_type(2)));

#if defined(__has_builtin)
#if __has_builtin(__builtin_amdgcn_cvt_f32_fp8) && __has_builtin(__builtin_amdgcn_cvt_pk_fp8_f32)
#define HAVE_HW_FP8 1
#endif
#if __has_builtin(__builtin_amdgcn_cvt_pk_f32_fp8)
#define HAVE_HW_FP8_PK 1
#endif
#endif

__device__ __forceinline__ float wave_reduce_sum(float v) {
  #pragma unroll
  for (int off = 32; off > 0; off >>= 1) v += __shfl_down(v, off, 64);
  return v;
}

__device__ __forceinline__ float leaky02(float x) {
  return x > 0.0f ? x : 0.2f * x;
}

__device__ __forceinline__ float bf2f(unsigned short u) {
  union { unsigned int i; float f; } v; v.i = ((unsigned int)u) << 16; return v.f;
}
__device__ __forceinline__ unsigned short f2bf(float f) {
  union { float f; unsigned int i; } v; v.f = f;
  unsigned int b = v.i;
  return (unsigned short)((b + 0x7FFFu + ((b >> 16) & 1u)) >> 16);  // RNE
}

#ifndef HAVE_HW_FP8
__device__ __forceinline__ unsigned char f2fp8_1(float f) {
  unsigned int u = __float_as_uint(f);
  unsigned int s = u >> 31;
  u &= 0x7fffffffu;
  if (u > 0x43e00000u) u = 0x43e00000u;
  unsigned int b = u + (0x0007FFFFu + ((u >> 20) & 1u));
  int e = (int)(b >> 23) - 127;
  unsigned int m = (b >> 20) & 7u;
  unsigned char o;
  if (e < -9) o = 0;
  else if (e < -6) { int sh = -6 - e; o = (unsigned char)((8u | m) >> sh); }
  else if (e > 8) o = 0x7e;
  else o = (unsigned char)(((e + 7) << 3) | m);
  return o | (unsigned char)(s << 7);
}
#endif
__device__ __forceinline__ float fp8tof_1(unsigned char b) {
  unsigned int s = b >> 7, e = (b >> 3) & 15u, m = b & 7u;
  float v = (e == 0) ? (float)m * 0.001953125f
                     : (float)(8u + m) * __uint_as_float((117u + e) << 23);
  return s ? -v : v;
}

__device__ __forceinline__ unsigned char f2fp8(float f) {
#ifdef HAVE_HW_FP8
  return (unsigned char)(__builtin_amdgcn_cvt_pk_fp8_f32(f, f, 0u, false) & 0xffu);
#else
  return f2fp8_1(f);
#endif
}

// fused: a{0..3} += p * fp8x4(hw)  — packed decode when HW supports it
__device__ __forceinline__ void fma4_fp8(unsigned int hw, float p,
                                         float& a0, float& a1, float& a2, float& a3) {
#ifdef HAVE_HW_FP8_PK
  f32x2 lo = __builtin_amdgcn_cvt_pk_f32_fp8((int)hw, false);
  f32x2 hi = __builtin_amdgcn_cvt_pk_f32_fp8((int)hw, true);
  a0 = fmaf(p, lo.x, a0);
  a1 = fmaf(p, lo.y, a1);
  a2 = fmaf(p, hi.x, a2);
  a3 = fmaf(p, hi.y, a3);
#elif defined(HAVE_HW_FP8)
  a0 = fmaf(p, __builtin_amdgcn_cvt_f32_fp8(hw, 0), a0);
  a1 = fmaf(p, __builtin_amdgcn_cvt_f32_fp8(hw, 1), a1);
  a2 = fmaf(p, __builtin_amdgcn_cvt_f32_fp8(hw, 2), a2);
  a3 = fmaf(p, __builtin_amdgcn_cvt_f32_fp8(hw, 3), a3);
#else
  a0 = fmaf(p, fp8tof_1((unsigned char)(hw & 0xffu)), a0);
  a1 = fmaf(p, fp8tof_1((unsigned char)((hw >> 8) & 0xffu)), a1);
  a2 = fmaf(p, fp8tof_1((unsigned char)((hw >> 16) & 0xffu)), a2);
  a3 = fmaf(p, fp8tof_1((unsigned char)((hw >> 24) & 0xffu)), a3);
#endif
}

// ---------------------------------------------------------------------------
// bpart: [preamble] W transposes + graph bounds (grid-stride), then partition
// edges into fixed-capacity buckets; pack src | (dstlocal<<16).
#define P3K 8
__global__ __launch_bounds__(256)
void bpart_kernel(const int* __restrict__ src, const int* __restrict__ dst,
                  int* __restrict__ bucketFill, unsigned int* __restrict__ bucketBuf,
                  const float* __restrict__ W1, const float* __restrict__ W2,
                  unsigned short* __restrict__ W1T, unsigned short* __restrict__ W2T,
                  const int* __restrict__ batch, int* __restrict__ gstart,
                  int* __restrict__ gend, int E, int N, int nbuck) {
  int tid = threadIdx.x;
  int stride = gridDim.x * 256;
  int t0 = blockIdx.x * 256 + tid;
  for (int u = t0; u < 256 * 128; u += stride) {   // W1T[n][k] = W1[k][n]
    int n = u >> 7, k = u & 127;
    W1T[u] = f2bf(W1[(size_t)k * 256 + n]);
  }
  for (int u = t0; u < 64 * 256; u += stride) {    // W2T[n][k] = W2[k][n]
    int n = u >> 8, k = u & 255;
    W2T[u] = f2bf(W2[(size_t)k * 64 + n]);
  }
  for (int i = t0; i < N; i += stride) {
    int g = batch[i];
    if (i == 0 || batch[i - 1] != g) gstart[g] = i;
    if (i == N - 1 || batch[i + 1] != g) gend[g] = i + 1;
  }

  __shared__ int lhist[256];
  __shared__ int lbase[256];
  int chunk = 256 * P3K;
  for (int start = blockIdx.x * chunk; start < E; start += gridDim.x * chunk) {
    lhist[tid] = 0;
    __syncthreads();
    int mybuck[P3K]; unsigned int mypack[P3K]; int myrank[P3K];
    #pragma unroll
    for (int k = 0; k < P3K; k++) {
      int i = start + k * 256 + tid;
      if (i < E) {
        int d = dst[i];
        int b = d >> 8;
        mybuck[k] = b;
        mypack[k] = (unsigned int)src[i] | ((unsigned int)(d & 255) << 16);
        myrank[k] = atomicAdd(&lhist[b], 1);
      } else mybuck[k] = -1;
    }
    __syncthreads();
    if (tid < nbuck) lbase[tid] = (lhist[tid] > 0) ? atomicAdd(&bucketFill[tid], lhist[tid]) : 0;
    __syncthreads();
    #pragma unroll
    for (int k = 0; k < P3K; k++) {
      if (mybuck[k] >= 0) {
        int b = mybuck[k];
        int pos = lbase[b] + myrank[k];
        if (pos < BCAP) bucketBuf[((size_t)b << 13) + pos] = mypack[k];
      }
    }
    __syncthreads();
  }
}

// ---------------------------------------------------------------------------
// merged bbuild + gemm1: blocks [0,nbuck) build per-bucket CSR; blocks
// [nbuck, nbuck+gridG) do GEMM1 (independent of CSR).
__global__ __launch_bounds__(256)
void bbuild_gemm1_kernel(const unsigned int* __restrict__ bucketBuf,
                         const int* __restrict__ bucketFill,
                         int* __restrict__ rowstart, int* __restrict__ rowend,
                         unsigned short* __restrict__ csr,
                         const float* __restrict__ X, const unsigned short* __restrict__ W1T,
                         unsigned char* __restrict__ h1f8,
                         const float* __restrict__ a_src, const float* __restrict__ a_dst,
                         float* __restrict__ asv, float* __restrict__ adv,
                         int N, int nbuck) {
  __shared__ union {
    struct { unsigned short As[64][136]; unsigned short Bs[256][40]; } g;
    struct { int ldeg[256]; int lscan[256]; int lfill[256]; } b;
  } sm;
  int tid = threadIdx.x;

  if (blockIdx.x < (unsigned)nbuck) {
    // ---- bbuild path ----
    int b = blockIdx.x;
    int r0 = b << 13;
    int cnt = bucketFill[b]; if (cnt > BCAP) cnt = BCAP;
    int nb0 = b << 8;
    sm.b.ldeg[tid] = 0;
    __syncthreads();
    for (int j = tid; j < cnt; j += 256)
      atomicAdd(&sm.b.ldeg[bucketBuf[r0 + j] >> 16], 1);
    __syncthreads();
    int v = sm.b.ldeg[tid];
    sm.b.lscan[tid] = v;
    __syncthreads();
    for (int off = 1; off < 256; off <<= 1) {
      int u = (tid >= off) ? sm.b.lscan[tid - off] : 0;
      __syncthreads();
      sm.b.lscan[tid] += u;
      __syncthreads();
    }
    int excl = sm.b.lscan[tid] - v;
    sm.b.lfill[tid] = excl;
    if (nb0 + tid < N) {
      rowstart[nb0 + tid] = r0 + excl;
      rowend[nb0 + tid]   = r0 + excl + v;
    }
    __syncthreads();
    for (int j = tid; j < cnt; j += 256) {
      unsigned int p = bucketBuf[r0 + j];
      int pos = r0 + atomicAdd(&sm.b.lfill[p >> 16], 1);
      csr[pos] = (unsigned short)(p & 0xffffu);
    }
    return;
  }

  // ---- gemm1 path ----
  int t = tid;
  int w = t >> 6, lane = t & 63;
  int quad = lane >> 4, l16 = lane & 15;
  int blockRow = (blockIdx.x - nbuck) * 64;

  {
    int node = t >> 2, kp = (t & 3) * 32;
    int gn = blockRow + node; if (gn >= N) gn = N - 1;
    const float4* xp = (const float4*)(X + (size_t)gn * 128 + kp);
    #pragma unroll
    for (int i = 0; i < 4; i++) {
      float4 va = xp[2 * i], vb = xp[2 * i + 1];
      union { unsigned short u[8]; uint4 v; } r;
      r.u[0] = f2bf(va.x); r.u[1] = f2bf(va.y); r.u[2] = f2bf(va.z); r.u[3] = f2bf(va.w);
      r.u[4] = f2bf(vb.x); r.u[5] = f2bf(vb.y); r.u[6] = f2bf(vb.z); r.u[7] = f2bf(vb.w);
      *(uint4*)&sm.g.As[node][kp + i * 8] = r.v;
    }
  }

  f32x4 acc[4][4];
  #pragma unroll
  for (int i = 0; i < 4; i++)
    #pragma unroll
    for (int j = 0; j < 4; j++) acc[i][j] = (f32x4){0.f, 0.f, 0.f, 0.f};

  for (int kc = 0; kc < FIN; kc += 32) {
    {
      const unsigned short* wp = W1T + (size_t)t * 128 + kc;
      #pragma unroll
      for (int i = 0; i < 4; i++) {
        uint4 v = *(const uint4*)(wp + i * 8);
        *(uint4*)&sm.g.Bs[t][i * 8] = v;
      }
    }
    __syncthreads();
    bf16x8 af[4], bfr[4];
    #pragma unroll
    for (int mt = 0; mt < 4; mt++)
      af[mt] = *(const bf16x8*)&sm.g.As[mt * 16 + l16][kc + quad * 8];
    #pragma unroll
    for (int nt = 0; nt < 4; nt++)
      bfr[nt] = *(const bf16x8*)&sm.g.Bs[w * 64 + nt * 16 + l16][quad * 8];
    #pragma unroll
    for (int mt = 0; mt < 4; mt++)
      #pragma unroll
      for (int nt = 0; nt < 4; nt++)
        acc[mt][nt] = __builtin_amdgcn_mfma_f32_16x16x32_bf16(af[mt], bfr[nt], acc[mt][nt], 0, 0, 0);
    __syncthreads();
  }

  float a_s[4], a_d[4];
  #pragma unroll
  for (int nt = 0; nt < 4; nt++) {
    a_s[nt] = a_src[w * 64 + nt * 16 + l16];
    a_d[nt] = a_dst[w * 64 + nt * 16 + l16];
  }
  #pragma unroll
  for (int mt = 0; mt < 4; mt++) {
    #pragma unroll
    for (int reg = 0; reg < 4; reg++) {
      int node = blockRow + mt * 16 + quad * 4 + reg;
      bool ok = node < N;
      float ps = 0.0f, pd = 0.0f;
      #pragma unroll
      for (int nt = 0; nt < 4; nt++) {
        float v = acc[mt][nt][reg];
        ps = fmaf(v, a_s[nt], ps);
        pd = fmaf(v, a_d[nt], pd);
        if (ok) h1f8[(size_t)node * 256 + w * 64 + nt * 16 + l16] = f2fp8(v);
      }
      #pragma unroll
      for (int off = 8; off > 0; off >>= 1) {
        ps += __shfl_xor(ps, off, 16);
        pd += __shfl_xor(pd, off, 16);
      }
      if (l16 == 0 && ok) {
        asv[(size_t)node * 4 + w] = ps;
        adv[(size_t)node * 4 + w] = pd;
      }
    }
  }
}

// GEMM2 (MFMA bf16): h2lin = out1b[N,256] @ W2T^T -> fp8; fused attn2.
__global__ __launch_bounds__(256)
void gemm2_kernel(const unsigned short* __restrict__ out1b, const unsigned short* __restrict__ W2T,
                  unsigned char* __restrict__ h2f8,
                  const float* __restrict__ a_src, const float* __restrict__ a_dst,
                  float* __restrict__ asv, float* __restrict__ adv, int N) {
  __shared__ unsigned short As[64][40];
  __shared__ unsigned short Bs[64][40];
  int t = threadIdx.x;
  int w = t >> 6, lane = t & 63;
  int quad = lane >> 4, l16 = lane & 15;
  int blockRow = blockIdx.x * 64;

  f32x4 acc[4];
  #pragma unroll
  for (int j = 0; j < 4; j++) acc[j] = (f32x4){0.f, 0.f, 0.f, 0.f};

  int nodeS = t >> 2, koff = (t & 3) * 8;
  int gnS = blockRow + nodeS; if (gnS >= N) gnS = N - 1;

  for (int kc = 0; kc < 256; kc += 32) {
    {
      uint4 va = *(const uint4*)(out1b + (size_t)gnS * 256 + kc + koff);
      *(uint4*)&As[nodeS][koff] = va;
      uint4 vb = *(const uint4*)(W2T + (size_t)nodeS * 256 + kc + koff);
      *(uint4*)&Bs[nodeS][koff] = vb;
    }
    __syncthreads();
    bf16x8 af = *(const bf16x8*)&As[w * 16 + l16][quad * 8];
    #pragma unroll
    for (int nt = 0; nt < 4; nt++) {
      bf16x8 bfr = *(const bf16x8*)&Bs[nt * 16 + l16][quad * 8];
      acc[nt] = __builtin_amdgcn_mfma_f32_16x16x32_bf16(af, bfr, acc[nt], 0, 0, 0);
    }
    __syncthreads();
  }

  float a_s[4], a_d[4];
  #pragma unroll
  for (int nt = 0; nt < 4; nt++) {
    a_s[nt] = a_src[nt * 16 + l16];
    a_d[nt] = a_dst[nt * 16 + l16];
  }
  #pragma unroll
  for (int reg = 0; reg < 4; reg++) {
    int node = blockRow + w * 16 + quad * 4 + reg;
    bool ok = node < N;
    float ps = 0.0f, pd = 0.0f;
    #pragma unroll
    for (int nt = 0; nt < 4; nt++) {
      float v = acc[nt][reg];
      ps = fmaf(v, a_s[nt], ps);
      pd = fmaf(v, a_d[nt], pd);
      if (ok) h2f8[(size_t)node * 64 + nt * 16 + l16] = f2fp8(v);
    }
    #pragma unroll
    for (int off = 8; off > 0; off >>= 1) {
      ps += __shfl_xor(ps, off, 16);
      pd += __shfl_xor(pd, off, 16);
    }
    if (l16 == 0 && ok) { asv[node] = ps; adv[node] = pd; }
  }
}

// ---------------------------------------------------------------------------
// aggregation layer 1: softmax with m=0; per-lane psum; scalar-addressed
// uniform-row gathers (readfirstlane), 8 in flight. ssum accumulated
// in-loop (every lane sees every edge's p[hsel]) — no shuffle reduction.
__global__ __launch_bounds__(256)
void agg1_kernel(const unsigned char* __restrict__ h1f8, const int* __restrict__ rowstart,
                 const int* __restrict__ rowend, const unsigned short* __restrict__ csr,
                 const float* __restrict__ asv, const float* __restrict__ adv,
                 const float* __restrict__ b1, unsigned short* __restrict__ out1b, int N) {
  __shared__ int   sbuf[4][64];
  __shared__ float pbuf[4][4][68];   // [wave][head][edge]
  int wv   = threadIdx.x >> 6;
  int lane = threadIdx.x & 63;
  int n = blockIdx.x * 4 + wv;
  if (n >= N) return;
  int r0 = rowstart[n], r1 = rowend[n];
  float4 ad = *(const float4*)(adv + (size_t)n * 4);
  float4 asn = *(const float4*)(asv + (size_t)n * 4);
  int hsel = lane >> 4;

  float es0 = leaky02(asn.x + ad.x);
  float es1 = leaky02(asn.y + ad.y);
  float es2 = leaky02(asn.z + ad.z);
  float es3 = leaky02(asn.w + ad.w);
  float esel = hsel == 0 ? es0 : (hsel == 1 ? es1 : (hsel == 2 ? es2 : es3));

  float ssum = 0.0f;
  float a0 = 0, a1 = 0, a2 = 0, a3 = 0;

  for (int base = r0; base < r1; base += 64) {
    int j = base + lane;
    int cnt = min(64, r1 - base);
    if (j < r1) {
      int s = csr[j];
      float4 as = *(const float4*)(asv + (size_t)s * 4);
      sbuf[wv][lane] = s;
      pbuf[wv][0][lane] = __expf(leaky02(as.x + ad.x));
      pbuf[wv][1][lane] = __expf(leaky02(as.y + ad.y));
      pbuf[wv][2][lane] = __expf(leaky02(as.z + ad.z));
      pbuf[wv][3][lane] = __expf(leaky02(as.w + ad.w));
    }
    __threadfence_block();

    int c = 0;
    for (; c + 8 <= cnt; c += 8) {
      int4 sv0 = *(const int4*)&sbuf[wv][c];
      int4 sv1 = *(const int4*)&sbuf[wv][c + 4];
      int sc0 = __builtin_amdgcn_readfirstlane(sv0.x);
      int sc1 = __builtin_amdgcn_readfirstlane(sv0.y);
      int sc2 = __builtin_amdgcn_readfirstlane(sv0.z);
      int sc3 = __builtin_amdgcn_readfirstlane(sv0.w);
      int sc4 = __builtin_amdgcn_readfirstlane(sv1.x);
      int sc5 = __builtin_amdgcn_readfirstlane(sv1.y);
      int sc6 = __builtin_amdgcn_readfirstlane(sv1.z);
      int sc7 = __builtin_amdgcn_readfirstlane(sv1.w);
      unsigned int hw0 = *((const unsigned int*)(h1f8 + ((size_t)sc0 << 8)) + lane);
      unsigned int hw1 = *((const unsigned int*)(h1f8 + ((size_t)sc1 << 8)) + lane);
      unsigned int hw2 = *((const unsigned int*)(h1f8 + ((size_t)sc2 << 8)) + lane);
      unsigned int hw3 = *((const unsigned int*)(h1f8 + ((size_t)sc3 << 8)) + lane);
      unsigned int hw4 = *((const unsigned int*)(h1f8 + ((size_t)sc4 << 8)) + lane);
      unsigned int hw5 = *((const unsigned int*)(h1f8 + ((size_t)sc5 << 8)) + lane);
      unsigned int hw6 = *((const unsigned int*)(h1f8 + ((size_t)sc6 << 8)) + lane);
      unsigned int hw7 = *((const unsigned int*)(h1f8 + ((size_t)sc7 << 8)) + lane);
      float4 pva = *(const float4*)&pbuf[wv][hsel][c];
      float4 pvb = *(const float4*)&pbuf[wv][hsel][c + 4];
      ssum += (pva.x + pva.y) + (pva.z + pva.w) + (pvb.x + pvb.y) + (pvb.z + pvb.w);
      fma4_fp8(hw0, pva.x, a0, a1, a2, a3);
      fma4_fp8(hw1, pva.y, a0, a1, a2, a3);
      fma4_fp8(hw2, pva.z, a0, a1, a2, a3);
      fma4_fp8(hw3, pva.w, a0, a1, a2, a3);
      fma4_fp8(hw4, pvb.x, a0, a1, a2, a3);
      fma4_fp8(hw5, pvb.y, a0, a1, a2, a3);
      fma4_fp8(hw6, pvb.z, a0, a1, a2, a3);
      fma4_fp8(hw7, pvb.w, a0, a1, a2, a3);
    }
    for (; c + 4 <= cnt; c += 4) {
      int4 sv = *(const int4*)&sbuf[wv][c];
      int sc0 = __builtin_amdgcn_readfirstlane(sv.x);
      int sc1 = __builtin_amdgcn_readfirstlane(sv.y);
      int sc2 = __builtin_amdgcn_readfirstlane(sv.z);
      int sc3 = __builtin_amdgcn_readfirstlane(sv.w);
      unsigned int hw0 = *((const unsigned int*)(h1f8 + ((size_t)sc0 << 8)) + lane);
      unsigned int hw1 = *((const unsigned int*)(h1f8 + ((size_t)sc1 << 8)) + lane);
      unsigned int hw2 = *((const unsigned int*)(h1f8 + ((size_t)sc2 << 8)) + lane);
      unsigned int hw3 = *((const unsigned int*)(h1f8 + ((size_t)sc3 << 8)) + lane);
      float4 pv = *(const float4*)&pbuf[wv][hsel][c];
      ssum += (pv.x + pv.y) + (pv.z + pv.w);
      fma4_fp8(hw0, pv.x, a0, a1, a2, a3);
      fma4_fp8(hw1, pv.y, a0, a1, a2, a3);
      fma4_fp8(hw2, pv.z, a0, a1, a2, a3);
      fma4_fp8(hw3, pv.w, a0, a1, a2, a3);
    }
    for (; c < cnt; c++) {
      int sc = __builtin_amdgcn_readfirstlane(sbuf[wv][c]);
      float psel = pbuf[wv][hsel][c];
      unsigned int hw = *((const unsigned int*)(h1f8 + ((size_t)sc << 8)) + lane);
      ssum += psel;
      fma4_fp8(hw, psel, a0, a1, a2, a3);
    }
    __threadfence_block();
  }

  {
    float psel = __expf(esel);   // self-loop
    ssum += psel;
    unsigned int hw = *((const unsigned int*)(h1f8 + ((size_t)n << 8)) + lane);
    fma4_fp8(hw, psel, a0, a1, a2, a3);
  }

  float inv = 1.0f / (ssum + 1e-16f);
  int d0 = lane * 4;
  float4 bv = *(const float4*)(b1 + d0);
  float v0 = a0 * inv + bv.x;
  float v1 = a1 * inv + bv.y;
  float v2 = a2 * inv + bv.z;
  float v3 = a3 * inv + bv.w;
  ushort4 o;
  o.x = f2bf(v0 > 0 ? v0 : 0.0f);
  o.y = f2bf(v1 > 0 ? v1 : 0.0f);
  o.z = f2bf(v2 > 0 ? v2 : 0.0f);
  o.w = f2bf(v3 > 0 ? v3 : 0.0f);
  *(ushort4*)(out1b + (size_t)n * 256 + d0) = o;
}

// aggregation layer 2: m=0; 8 lanes per edge via dwordx2 (8 edges per load
// instr); accumulators cover 8 dims/lane; reduction xor{8,16,32}; q counted
// once per edge per l8-slice. h2 output stored bf16.
__global__ __launch_bounds__(256)
void agg2_kernel(const unsigned char* __restrict__ h2f8, const int* __restrict__ rowstart,
                 const int* __restrict__ rowend, const unsigned short* __restrict__ csr,
                 const float* __restrict__ asv, const float* __restrict__ adv,
                 const float* __restrict__ b2, unsigned short* __restrict__ h2b, int N) {
  __shared__ int   sbuf[4][64];
  __shared__ float pbuf[4][64];
  int wv   = threadIdx.x >> 6;
  int lane = threadIdx.x & 63;
  int e8 = lane >> 3, l8 = lane & 7;   // edge slot / dim-octet
  int n = blockIdx.x * 4 + wv;
  if (n >= N) return;
  int r0 = rowstart[n], r1 = rowend[n];
  float ad = adv[n];
  float eself = leaky02(asv[n] + ad);
  float q = 0.0f;
  float a0 = 0, a1 = 0, a2 = 0, a3 = 0, a4 = 0, a5 = 0, a6 = 0, a7 = 0;

  for (int base = r0; base < r1; base += 64) {
    int j = base + lane;
    int cnt = min(64, r1 - base);
    if (j < r1) {
      int s = csr[j];
      sbuf[wv][lane] = s;
      pbuf[wv][lane] = __expf(leaky02(asv[s] + ad));
    }
    __threadfence_block();

    int c = 0;
    for (; c + 16 <= cnt; c += 16) {
      int scA = sbuf[wv][c + e8];
      int scB = sbuf[wv][c + 8 + e8];
      float pA = pbuf[wv][c + e8];
      float pB = pbuf[wv][c + 8 + e8];
      uint2 hwA = *(const uint2*)(h2f8 + ((size_t)scA << 6) + l8 * 8);
      uint2 hwB = *(const uint2*)(h2f8 + ((size_t)scB << 6) + l8 * 8);
      q += pA + pB;
      fma4_fp8(hwA.x, pA, a0, a1, a2, a3);
      fma4_fp8(hwA.y, pA, a4, a5, a6, a7);
      fma4_fp8(hwB.x, pB, a0, a1, a2, a3);
      fma4_fp8(hwB.y, pB, a4, a5, a6, a7);
    }
    for (; c + 8 <= cnt; c += 8) {
      int sc = sbuf[wv][c + e8];
      float p1 = pbuf[wv][c + e8];
      uint2 hw = *(const uint2*)(h2f8 + ((size_t)sc << 6) + l8 * 8);
      q += p1;
      fma4_fp8(hw.x, p1, a0, a1, a2, a3);
      fma4_fp8(hw.y, p1, a4, a5, a6, a7);
    }
    int rem = cnt - c;
    if (e8 < rem) {
      int sc = sbuf[wv][c + e8];
      float p1 = pbuf[wv][c + e8];
      uint2 hw = *(const uint2*)(h2f8 + ((size_t)sc << 6) + l8 * 8);
      q += p1;
      fma4_fp8(hw.x, p1, a0, a1, a2, a3);
      fma4_fp8(hw.y, p1, a4, a5, a6, a7);
    }
    __threadfence_block();
  }

  // reduce across the 8 edge-slot groups (each l8 slice counts each edge once)
  #pragma unroll
  for (int off = 8; off <= 32; off <<= 1) {
    q  += __shfl_xor(q,  off, 64);
    a0 += __shfl_xor(a0, off, 64);
    a1 += __shfl_xor(a1, off, 64);
    a2 += __shfl_xor(a2, off, 64);
    a3 += __shfl_xor(a3, off, 64);
    a4 += __shfl_xor(a4, off, 64);
    a5 += __shfl_xor(a5, off, 64);
    a6 += __shfl_xor(a6, off, 64);
    a7 += __shfl_xor(a7, off, 64);
  }
  float ssum = q;

  {
    float p = __expf(eself);   // self-loop (after reduction: every lane adds once)
    ssum += p;
    uint2 hw = *(const uint2*)(h2f8 + ((size_t)n << 6) + l8 * 8);
    fma4_fp8(hw.x, p, a0, a1, a2, a3);
    fma4_fp8(hw.y, p, a4, a5, a6, a7);
  }

  if (e8 == 0) {
    float inv = 1.0f / (ssum + 1e-16f);
    int d0 = l8 * 8;
    float4 bva = *(const float4*)(b2 + d0);
    float4 bvb = *(const float4*)(b2 + d0 + 4);
    float v0 = a0 * inv + bva.x;
    float v1 = a1 * inv + bva.y;
    float v2 = a2 * inv + bva.z;
    float v3 = a3 * inv + bva.w;
    float v4 = a4 * inv + bvb.x;
    float v5 = a5 * inv + bvb.y;
    float v6 = a6 * inv + bvb.z;
    float v7 = a7 * inv + bvb.w;
    union { unsigned short u[8]; uint4 v; } o;
    o.u[0] = f2bf(v0 > 0 ? v0 : 0.0f);
    o.u[1] = f2bf(v1 > 0 ? v1 : 0.0f);
    o.u[2] = f2bf(v2 > 0 ? v2 : 0.0f);
    o.u[3] = f2bf(v3 > 0 ? v3 : 0.0f);
    o.u[4] = f2bf(v4 > 0 ? v4 : 0.0f);
    o.u[5] = f2bf(v5 > 0 ? v5 : 0.0f);
    o.u[6] = f2bf(v6 > 0 ? v6 : 0.0f);
    o.u[7] = f2bf(v7 > 0 ? v7 : 0.0f);
    *(uint4*)(h2b + (size_t)n * 64 + d0) = o.v;
  }
}

// ---------------------------------------------------------------------------
// mean pool (bf16 h2, vectorized uint loads: 2 dims/lane) + classifier +
// log_softmax; one 4-wave block per graph
__global__ __launch_bounds__(256)
void pool_kernel(const unsigned short* __restrict__ h2b, const int* __restrict__ gstart,
                 const int* __restrict__ gend, const float* __restrict__ Wc,
                 const float* __restrict__ bc, float* __restrict__ out) {
  int g = blockIdx.x;
  int w = threadIdx.x >> 6, lane = threadIdx.x & 63;
  int s = gstart[g], e = gend[g];
  // lane owns dims (2*lane, 2*lane+1)
  float acc0 = 0.0f, acc1 = 0.0f;
  for (int n = s + w; n < e; n += 4) {
    unsigned int v = *(const unsigned int*)(h2b + (size_t)n * 64 + lane * 2);
    acc0 += __uint_as_float(v << 16);
    acc1 += __uint_as_float(v & 0xffff0000u);
  }
  __shared__ float red0[4][64];
  __shared__ float red1[4][64];
  red0[w][lane] = acc0;
  red1[w][lane] = acc1;
  __syncthreads();
  if (w == 0) {
    float v0 = red0[0][lane] + red0[1][lane] + red0[2][lane] + red0[3][lane];
    float v1 = red1[0][lane] + red1[1][lane] + red1[2][lane] + red1[3][lane];
    float invc = (e > s) ? 1.0f / (float)(e - s) : 0.0f;
    float p0 = v0 * invc, p1 = v1 * invc;
    int d0 = lane * 2;
    float l0 = wave_reduce_sum(fmaf(p0, Wc[d0 * 2 + 0], p1 * Wc[(d0 + 1) * 2 + 0]));
    float l1 = wave_reduce_sum(fmaf(p0, Wc[d0 * 2 + 1], p1 * Wc[(d0 + 1) * 2 + 1]));
    if (lane == 0) {
      l0 += bc[0]; l1 += bc[1];
      float mx = fmaxf(l0, l1);
      float lse = mx + logf(__expf(l0 - mx) + __expf(l1 - mx));
      out[g * 2 + 0] = l0 - lse;
      out[g * 2 + 1] = l1 - lse;
    }
  }
}

// ---------------------------------------------------------------------------
extern "C" void kernel_launch(void* const* d_in, const int* in_sizes, int n_in,
                              void* d_out, int out_size, void* d_ws, size_t ws_size,
                              hipStream_t stream) {
  const float* x      = (const float*)d_in[0];
  const int*   ei     = (const int*)d_in[1];
  const int*   batch  = (const int*)d_in[2];
  const float* W1     = (const float*)d_in[3];
  const float* a_src1 = (const float*)d_in[4];
  const float* a_dst1 = (const float*)d_in[5];
  const float* b1     = (const float*)d_in[6];
  const float* W2     = (const float*)d_in[7];
  const float* a_src2 = (const float*)d_in[8];
  const float* a_dst2 = (const float*)d_in[9];
  const float* b2     = (const float*)d_in[10];
  const float* Wc     = (const float*)d_in[11];
  const float* bc     = (const float*)d_in[12];
  float* out = (float*)d_out;

  const int N = in_sizes[0] / FIN;      // 50000
  const int E = in_sizes[1] / 2;        // 800000
  const int* srcArr = ei;
  const int* dstArr = ei + E;
  const int nbuck = (N + 255) >> 8;     // 196

  char* base = (char*)d_ws;
  size_t off = 0;
  auto alloc = [&](size_t bytes) -> void* {
    void* p = base + off;
    off = (off + bytes + 255) & ~(size_t)255;
    return p;
  };
  unsigned short* W1T  = (unsigned short*)alloc((size_t)256 * 128 * 2);
  unsigned short* W2T  = (unsigned short*)alloc((size_t)64 * 256 * 2);
  unsigned char*  h1f8 = (unsigned char*)alloc((size_t)N * 256);
  unsigned short* out1b= (unsigned short*)alloc((size_t)N * 256 * 2);
  unsigned char*  h2f8 = (unsigned char*)alloc((size_t)N * 64);
  unsigned short* h2b  = (unsigned short*)alloc((size_t)N * 64 * 2);
  float* asv1  = (float*)alloc((size_t)N * 4 * 4);
  float* adv1  = (float*)alloc((size_t)N * 4 * 4);
  float* asv2  = (float*)alloc((size_t)N * 4);
  float* adv2  = (float*)alloc((size_t)N * 4);
  // zero-init region: bucketFill, gstart, gend contiguous
  int*   bucketFill= (int*)alloc(256 * 4);
  int*   gstart= (int*)alloc(NGRAPH * 4);
  int*   gend  = (int*)alloc(NGRAPH * 4);
  size_t zspan = (size_t)((char*)gend + NGRAPH * 4 - (char*)bucketFill);
  int*   rowstart = (int*)alloc((size_t)N * 4);
  int*   rowend   = (int*)alloc((size_t)N * 4);
  unsigned int* bucketBuf = (unsigned int*)alloc((size_t)nbuck * BCAP * 4);
  unsigned short* csr = (unsigned short*)alloc((size_t)nbuck * BCAP * 2);
  (void)ws_size; (void)n_in; (void)out_size;

  int gridWv = (N + 3) / 4;
  int gridG  = (N + 63) / 64;
  int gridP3 = (E + 256 * P3K - 1) / (256 * P3K);
  if (gridP3 > 1024) gridP3 = 1024;

  hipMemsetAsync(bucketFill, 0, zspan, stream);
  bpart_kernel<<<gridP3, 256, 0, stream>>>(srcArr, dstArr, bucketFill, bucketBuf,
                                           W1, W2, W1T, W2T, batch, gstart, gend,
                                           E, N, nbuck);
  // merged: CSR build (blocks < nbuck) + GEMM1 (rest)
  bbuild_gemm1_kernel<<<nbuck + gridG, 256, 0, stream>>>(
      bucketBuf, bucketFill, rowstart, rowend, csr,
      x, W1T, h1f8, a_src1, a_dst1, asv1, adv1, N, nbuck);
  agg1_kernel<<<gridWv, 256, 0, stream>>>(h1f8, rowstart, rowend, csr, asv1, adv1, b1, out1b, N);

  // layer 2
  gemm2_kernel<<<gridG, 256, 0, stream>>>(out1b, W2T, h2f8, a_src2, a_dst2, asv2, adv2, N);
  agg2_kernel<<<gridWv, 256, 0, stream>>>(h2f8, rowstart, rowend, csr, asv2, adv2, b2, h2b, N);

  // pool + classify
  pool_kernel<<<NGRAPH, 256, 0, stream>>>(h2b, gstart, gend, Wc, bc, out);
}